// Round 1
// baseline (7609.541 us; speedup 1.0000x reference)
//
#include <hip/hip_runtime.h>
#include <math.h>

// Problem constants
#define NB 8
#define SEQ 1024
#define DM 512
#define NH 8
#define HDIM 64
#define DFF 2048
#define NLAYER 4
#define NTOK (NB * SEQ)   // 8192

// ---------------------------------------------------------------------------
// Positional encoding add: out = x + PE  (one float4 per thread)
// ---------------------------------------------------------------------------
__global__ __launch_bounds__(256) void add_pos_kernel(const float* __restrict__ x,
                                                      float* __restrict__ out) {
    int idx4 = blockIdx.x * blockDim.x + threadIdx.x;
    int base = idx4 * 4;
    int d = base & (DM - 1);
    int s = (base >> 9) & (SEQ - 1);
    float4 v = *(const float4*)&x[base];
    float r[4] = {v.x, v.y, v.z, v.w};
#pragma unroll
    for (int i = 0; i < 4; i++) {
        int dd = d + i;
        float pe;
        if (dd < 256) {
            float inv = powf(10000.0f, 2.0f * (float)dd / 512.0f);
            pe = sinf((float)s / inv);
        } else {
            float inv = powf(10000.0f, 2.0f * (float)(dd - 256) / 512.0f);
            pe = cosf((float)s / inv);
        }
        r[i] += pe;
    }
    *(float4*)&out[base] = make_float4(r[0], r[1], r[2], r[3]);
}

// ---------------------------------------------------------------------------
// LayerNorm: one wave per row (D=512), 4 rows per 256-thread block.
// Two-pass (matches reference mean / mean((x-mu)^2)).
// ---------------------------------------------------------------------------
__global__ __launch_bounds__(256) void ln_kernel(const float* __restrict__ x,
                                                 const float* __restrict__ g,
                                                 const float* __restrict__ bta,
                                                 float* __restrict__ out) {
    int w = threadIdx.x >> 6;
    int lane = threadIdx.x & 63;
    size_t row = (size_t)blockIdx.x * 4 + w;
    const float* xr = x + row * DM;
    float4 v0 = *(const float4*)&xr[lane * 4];
    float4 v1 = *(const float4*)&xr[256 + lane * 4];
    float sum = v0.x + v0.y + v0.z + v0.w + v1.x + v1.y + v1.z + v1.w;
#pragma unroll
    for (int off = 32; off > 0; off >>= 1) sum += __shfl_xor(sum, off, 64);
    float mu = sum * (1.0f / 512.0f);
    float d0[8] = {v0.x - mu, v0.y - mu, v0.z - mu, v0.w - mu,
                   v1.x - mu, v1.y - mu, v1.z - mu, v1.w - mu};
    float sq = 0.0f;
#pragma unroll
    for (int i = 0; i < 8; i++) sq = fmaf(d0[i], d0[i], sq);
#pragma unroll
    for (int off = 32; off > 0; off >>= 1) sq += __shfl_xor(sq, off, 64);
    float rs = rsqrtf(sq * (1.0f / 512.0f) + 1e-3f);
    float4 g0 = *(const float4*)&g[lane * 4];
    float4 g1 = *(const float4*)&g[256 + lane * 4];
    float4 b0 = *(const float4*)&bta[lane * 4];
    float4 b1 = *(const float4*)&bta[256 + lane * 4];
    float* orow = out + row * DM;
    *(float4*)&orow[lane * 4] = make_float4(
        fmaf(d0[0] * rs, g0.x, b0.x), fmaf(d0[1] * rs, g0.y, b0.y),
        fmaf(d0[2] * rs, g0.z, b0.z), fmaf(d0[3] * rs, g0.w, b0.w));
    *(float4*)&orow[256 + lane * 4] = make_float4(
        fmaf(d0[4] * rs, g1.x, b1.x), fmaf(d0[5] * rs, g1.y, b1.y),
        fmaf(d0[6] * rs, g1.z, b1.z), fmaf(d0[7] * rs, g1.w, b1.w));
}

// ---------------------------------------------------------------------------
// Tiled fp32 GEMM: C[M,N] (+)= op(A[M,K] @ W[K,N] + bias)
// 128x128 block tile, BK=16, 256 threads, 8x8 micro-tile (split 4+4 across
// the 64-col halves for conflict-free float4 LDS reads).
// ---------------------------------------------------------------------------
template <bool BIAS, bool RELU, bool RES>
__global__ __launch_bounds__(256) void gemm_kernel(const float* __restrict__ A,
                                                   const float* __restrict__ W,
                                                   const float* __restrict__ bias,
                                                   float* __restrict__ C,
                                                   int M, int N, int K) {
    __shared__ __align__(16) float As[16][132];  // transposed A tile, padded
    __shared__ __align__(16) float Bs[16][128];
    const int tid = threadIdx.x;
    const int tx = tid & 15;
    const int ty = tid >> 4;
    const int m0 = blockIdx.y * 128;
    const int n0 = blockIdx.x * 128;

    float acc[8][8];
#pragma unroll
    for (int i = 0; i < 8; i++)
#pragma unroll
        for (int j = 0; j < 8; j++) acc[i][j] = 0.0f;

    for (int kt = 0; kt < K; kt += 16) {
#pragma unroll
        for (int u = 0; u < 2; u++) {
            int q = tid + u * 256;
            int row = q >> 2;
            int c4 = (q & 3) * 4;
            float4 av = *(const float4*)&A[(size_t)(m0 + row) * K + kt + c4];
            As[c4 + 0][row] = av.x;
            As[c4 + 1][row] = av.y;
            As[c4 + 2][row] = av.z;
            As[c4 + 3][row] = av.w;
            int rowb = q >> 5;
            int c4b = (q & 31) * 4;
            *(float4*)&Bs[rowb][c4b] =
                *(const float4*)&W[(size_t)(kt + rowb) * N + n0 + c4b];
        }
        __syncthreads();
#pragma unroll
        for (int kk = 0; kk < 16; kk++) {
            float4 a0 = *(float4*)&As[kk][ty * 4];
            float4 a1 = *(float4*)&As[kk][ty * 4 + 64];
            float4 b0 = *(float4*)&Bs[kk][tx * 4];
            float4 b1 = *(float4*)&Bs[kk][tx * 4 + 64];
            float a[8] = {a0.x, a0.y, a0.z, a0.w, a1.x, a1.y, a1.z, a1.w};
            float b[8] = {b0.x, b0.y, b0.z, b0.w, b1.x, b1.y, b1.z, b1.w};
#pragma unroll
            for (int i = 0; i < 8; i++)
#pragma unroll
                for (int j = 0; j < 8; j++)
                    acc[i][j] = fmaf(a[i], b[j], acc[i][j]);
        }
        __syncthreads();
    }

#pragma unroll
    for (int i8 = 0; i8 < 8; i8++) {
        int row = m0 + (i8 >> 2) * 64 + ty * 4 + (i8 & 3);
#pragma unroll
        for (int j4 = 0; j4 < 2; j4++) {
            int col = n0 + j4 * 64 + tx * 4;
            float4 r = make_float4(acc[i8][j4 * 4 + 0], acc[i8][j4 * 4 + 1],
                                   acc[i8][j4 * 4 + 2], acc[i8][j4 * 4 + 3]);
            if (BIAS) {
                float4 bv = *(const float4*)&bias[col];
                r.x += bv.x; r.y += bv.y; r.z += bv.z; r.w += bv.w;
            }
            if (RELU) {
                r.x = fmaxf(r.x, 0.0f); r.y = fmaxf(r.y, 0.0f);
                r.z = fmaxf(r.z, 0.0f); r.w = fmaxf(r.w, 0.0f);
            }
            float* cp = &C[(size_t)row * N + col];
            if (RES) {
                float4 old = *(float4*)cp;
                r.x += old.x; r.y += old.y; r.z += old.z; r.w += old.w;
            }
            *(float4*)cp = r;
        }
    }
}

// ---------------------------------------------------------------------------
// Attention: flash-style online softmax.
// Block = 256 threads = 4 waves; block handles one (b,h) and 16 q rows
// (4 rows per wave). K/V staged in LDS in 64-key tiles.
// Scores: lane = key j (q broadcast from registers via readlane).
// PV:     lane = (row-group rg, dim-quad d4), float4 V reads.
// ---------------------------------------------------------------------------
__global__ __launch_bounds__(256) void attn_kernel(const float* __restrict__ Q,
                                                   const float* __restrict__ K,
                                                   const float* __restrict__ V,
                                                   const int* __restrict__ mask,
                                                   float* __restrict__ O) {
    __shared__ __align__(16) float Kt[64][68];  // padded: balanced f4 reads
    __shared__ __align__(16) float Vt[64][64];
    __shared__ float ps[16][64];
    __shared__ int msk[64];

    const int tid = threadIdx.x;
    const int lane = tid & 63;
    const int w = tid >> 6;
    const int qt = blockIdx.x;
    const int h = blockIdx.y;
    const int b = blockIdx.z;
    const int q0 = qt * 16;

    // q fragments: lane = dim
    float qreg[4];
#pragma unroll
    for (int r = 0; r < 4; r++)
        qreg[r] = Q[(size_t)(b * SEQ + q0 + w * 4 + r) * DM + h * HDIM + lane];

    float m[4], l[4], alpha[4];
#pragma unroll
    for (int r = 0; r < 4; r++) { m[r] = -INFINITY; l[r] = 0.0f; }
    float4 o4 = make_float4(0.0f, 0.0f, 0.0f, 0.0f);
    const int rg = lane >> 4;
    const int d4 = (lane & 15) * 4;
    const float scale = 0.125f;  // 1/sqrt(64)

    for (int j0 = 0; j0 < SEQ; j0 += 64) {
        __syncthreads();  // protect K/V/ps tiles from previous iteration
#pragma unroll
        for (int u = 0; u < 4; u++) {
            int qi = tid + u * 256;
            int j = qi >> 4;
            int c = (qi & 15) * 4;
            size_t gidx = (size_t)(b * SEQ + j0 + j) * DM + h * HDIM + c;
            float4 kv = *(const float4*)&K[gidx];
            Kt[j][c + 0] = kv.x; Kt[j][c + 1] = kv.y;
            Kt[j][c + 2] = kv.z; Kt[j][c + 3] = kv.w;
            *(float4*)&Vt[j][c] = *(const float4*)&V[gidx];
        }
        if (tid < 64) msk[tid] = mask[b * SEQ + j0 + tid];
        __syncthreads();

        // ---- scores (lane = key j within tile) ----
        float s[4] = {0.0f, 0.0f, 0.0f, 0.0f};
#pragma unroll
        for (int dq = 0; dq < 16; dq++) {
            float4 kv = *(const float4*)&Kt[lane][dq * 4];
#pragma unroll
            for (int r = 0; r < 4; r++) {
                float qa = __shfl(qreg[r], dq * 4 + 0, 64);
                float qb = __shfl(qreg[r], dq * 4 + 1, 64);
                float qc = __shfl(qreg[r], dq * 4 + 2, 64);
                float qd = __shfl(qreg[r], dq * 4 + 3, 64);
                s[r] = fmaf(kv.x, qa, s[r]);
                s[r] = fmaf(kv.y, qb, s[r]);
                s[r] = fmaf(kv.z, qc, s[r]);
                s[r] = fmaf(kv.w, qd, s[r]);
            }
        }
        const bool valid = (msk[lane] != 0);
#pragma unroll
        for (int r = 0; r < 4; r++) {
            float sv = valid ? s[r] * scale : -1e9f;
            float tm = sv;
#pragma unroll
            for (int off = 32; off > 0; off >>= 1)
                tm = fmaxf(tm, __shfl_xor(tm, off, 64));
            float mn = fmaxf(m[r], tm);
            alpha[r] = __expf(m[r] - mn);
            float p = __expf(sv - mn);
            float tsum = p;
#pragma unroll
            for (int off = 32; off > 0; off >>= 1)
                tsum += __shfl_xor(tsum, off, 64);
            l[r] = l[r] * alpha[r] + tsum;
            m[r] = mn;
            ps[w * 4 + r][lane] = p;
        }
        __syncthreads();

        // ---- PV (lane = (row-group, dim-quad)) ----
        float4 acc = make_float4(0.0f, 0.0f, 0.0f, 0.0f);
#pragma unroll 8
        for (int j = 0; j < 64; j++) {
            float p = ps[w * 4 + rg][j];
            float4 vv = *(const float4*)&Vt[j][d4];
            acc.x = fmaf(p, vv.x, acc.x);
            acc.y = fmaf(p, vv.y, acc.y);
            acc.z = fmaf(p, vv.z, acc.z);
            acc.w = fmaf(p, vv.w, acc.w);
        }
        float a = alpha[rg];
        o4.x = fmaf(o4.x, a, acc.x);
        o4.y = fmaf(o4.y, a, acc.y);
        o4.z = fmaf(o4.z, a, acc.z);
        o4.w = fmaf(o4.w, a, acc.w);
    }

    float inv_l = 1.0f / l[rg];
    size_t row = (size_t)(b * SEQ + q0 + w * 4 + rg);
    *(float4*)&O[row * DM + h * HDIM + d4] =
        make_float4(o4.x * inv_l, o4.y * inv_l, o4.z * inv_l, o4.w * inv_l);
}

// ---------------------------------------------------------------------------
extern "C" void kernel_launch(void* const* d_in, const int* in_sizes, int n_in,
                              void* d_out, int out_size, void* d_ws, size_t ws_size,
                              hipStream_t stream) {
    const float* x_in = (const float*)d_in[0];
    const int* mask   = (const int*)d_in[1];
    const float* Wq   = (const float*)d_in[2];
    const float* Wk   = (const float*)d_in[3];
    const float* Wv   = (const float*)d_in[4];
    const float* Wo   = (const float*)d_in[5];
    const float* ln1g = (const float*)d_in[6];
    const float* ln1b = (const float*)d_in[7];
    const float* ln2g = (const float*)d_in[8];
    const float* ln2b = (const float*)d_in[9];
    const float* W1   = (const float*)d_in[10];
    const float* b1   = (const float*)d_in[11];
    const float* W2   = (const float*)d_in[12];
    const float* b2   = (const float*)d_in[13];

    float* x = (float*)d_out;          // residual stream, updated in place
    float* ws = (float*)d_ws;
    const size_t ACT = (size_t)NTOK * DM;  // 4M floats
    float* h  = ws;                     // LN output
    float* q  = ws + ACT;
    float* k  = ws + 2 * ACT;
    float* v  = ws + 3 * ACT;
    float* o  = ws + 4 * ACT;
    float* f1 = ws + ACT;               // overlaps q..o (dead during FFN), 16M floats

    // x = input + positional encoding
    add_pos_kernel<<<(NTOK * DM / 4) / 256, 256, 0, stream>>>(x_in, x);

    dim3 gProj(DM / 128, NTOK / 128);    // (4, 64)
    dim3 gFF1(DFF / 128, NTOK / 128);    // (16, 64)
    dim3 gAttn(SEQ / 16, NH, NB);        // (64, 8, 8)

    for (int lyr = 0; lyr < NLAYER; lyr++) {
        const size_t wOff  = (size_t)lyr * DM * DM;
        const size_t w1Off = (size_t)lyr * DM * DFF;
        const size_t w2Off = (size_t)lyr * DFF * DM;

        ln_kernel<<<NTOK / 4, 256, 0, stream>>>(x, ln1g + lyr * DM, ln1b + lyr * DM, h);
        gemm_kernel<false, false, false><<<gProj, 256, 0, stream>>>(
            h, Wq + wOff, nullptr, q, NTOK, DM, DM);
        gemm_kernel<false, false, false><<<gProj, 256, 0, stream>>>(
            h, Wk + wOff, nullptr, k, NTOK, DM, DM);
        gemm_kernel<false, false, false><<<gProj, 256, 0, stream>>>(
            h, Wv + wOff, nullptr, v, NTOK, DM, DM);
        attn_kernel<<<gAttn, 256, 0, stream>>>(q, k, v, mask, o);
        gemm_kernel<false, false, true><<<gProj, 256, 0, stream>>>(
            o, Wo + wOff, nullptr, x, NTOK, DM, DM);
        ln_kernel<<<NTOK / 4, 256, 0, stream>>>(x, ln2g + lyr * DM, ln2b + lyr * DM, h);
        gemm_kernel<true, true, false><<<gFF1, 256, 0, stream>>>(
            h, W1 + w1Off, b1 + (size_t)lyr * DFF, f1, NTOK, DFF, DM);
        gemm_kernel<true, false, true><<<gProj, 256, 0, stream>>>(
            f1, W2 + w2Off, b2 + (size_t)lyr * DM, x, NTOK, DM, DFF);
    }
}

// Round 2
// 1147.561 us; speedup vs baseline: 6.6311x; 6.6311x over previous
//
#include <hip/hip_runtime.h>
#include <math.h>

// Problem constants
#define NB 8
#define SEQ 1024
#define DM 512
#define NH 8
#define HDIM 64
#define DFF 2048
#define NLAYER 4
#define NTOK (NB * SEQ)   // 8192

typedef __attribute__((ext_vector_type(8))) short bf16x8;
typedef __attribute__((ext_vector_type(4))) float f32x4;

__device__ __forceinline__ ushort f2bf(float f) {
    union { float f; unsigned u; } v; v.f = f;
    unsigned r = (v.u + 0x7FFF + ((v.u >> 16) & 1)) >> 16;  // RNE
    return (ushort)r;
}

// async global->LDS, 16B per lane. LDS dest = wave-uniform base + lane*16;
// we pass per-lane (base + lane*16) which is consistent either way.
__device__ __forceinline__ void async16(const void* g, void* l) {
    __builtin_amdgcn_global_load_lds(
        (const __attribute__((address_space(1))) unsigned int*)g,
        (__attribute__((address_space(3))) unsigned int*)l, 16, 0, 0);
}

// ---------------------------------------------------------------------------
// Positional encoding add: x_out(fp32) = x_in + PE
// ---------------------------------------------------------------------------
__global__ __launch_bounds__(256) void add_pos_kernel(const float* __restrict__ x,
                                                      float* __restrict__ out) {
    int idx4 = blockIdx.x * blockDim.x + threadIdx.x;
    int base = idx4 * 4;
    int d = base & (DM - 1);
    int s = (base >> 9) & (SEQ - 1);
    float4 v = *(const float4*)&x[base];
    float r[4] = {v.x, v.y, v.z, v.w};
#pragma unroll
    for (int i = 0; i < 4; i++) {
        int dd = d + i;
        float pe;
        if (dd < 256) {
            float inv = powf(10000.0f, 2.0f * (float)dd / 512.0f);
            pe = sinf((float)s / inv);
        } else {
            float inv = powf(10000.0f, 2.0f * (float)(dd - 256) / 512.0f);
            pe = cosf((float)s / inv);
        }
        r[i] += pe;
    }
    *(float4*)&out[base] = make_float4(r[0], r[1], r[2], r[3]);
}

// ---------------------------------------------------------------------------
// Weight convert + transpose: src fp32 [L][K][N] -> dst bf16 [L][N][K]
// ---------------------------------------------------------------------------
__global__ __launch_bounds__(256) void wtrans_kernel(const float* __restrict__ src,
                                                     ushort* __restrict__ dst,
                                                     int K, int N) {
    __shared__ float tile[32][36];
    int l = blockIdx.z;
    int kb = blockIdx.y * 32, nb = blockIdx.x * 32;
    const float* s = src + (size_t)l * K * N;
    ushort* d = dst + (size_t)l * K * N;
    int r = threadIdx.x >> 3, c4 = (threadIdx.x & 7) * 4;
    float4 v = *(const float4*)&s[(size_t)(kb + r) * N + nb + c4];
    *(float4*)&tile[r][c4] = v;
    __syncthreads();
    ushort4 o;
    o.x = f2bf(tile[c4 + 0][r]);
    o.y = f2bf(tile[c4 + 1][r]);
    o.z = f2bf(tile[c4 + 2][r]);
    o.w = f2bf(tile[c4 + 3][r]);
    *(ushort4*)&d[(size_t)(nb + r) * K + kb + c4] = o;
}

// ---------------------------------------------------------------------------
// bf16 transpose per batch: v [8][1024][512] -> vT [8][512][1024]
// ---------------------------------------------------------------------------
__global__ __launch_bounds__(256) void vtrans_kernel(const ushort* __restrict__ v,
                                                     ushort* __restrict__ vT) {
    __shared__ ushort tile[32][36];
    int b = blockIdx.z;
    int s0 = blockIdx.y * 32, c0 = blockIdx.x * 32;
    int r = threadIdx.x >> 3, q4 = (threadIdx.x & 7) * 4;
    *(ushort4*)&tile[r][q4] =
        *(const ushort4*)&v[(size_t)(b * SEQ + s0 + r) * DM + c0 + q4];
    __syncthreads();
    ushort4 o;
    o.x = tile[q4 + 0][r];
    o.y = tile[q4 + 1][r];
    o.z = tile[q4 + 2][r];
    o.w = tile[q4 + 3][r];
    *(ushort4*)&vT[(size_t)(b * DM + c0 + r) * SEQ + s0 + q4] = o;
}

// ---------------------------------------------------------------------------
// LayerNorm fp32 in -> bf16 out. One wave per row, 4 rows/block.
// ---------------------------------------------------------------------------
__global__ __launch_bounds__(256) void ln_kernel(const float* __restrict__ x,
                                                 const float* __restrict__ g,
                                                 const float* __restrict__ bta,
                                                 ushort* __restrict__ out) {
    int w = threadIdx.x >> 6;
    int lane = threadIdx.x & 63;
    size_t row = (size_t)blockIdx.x * 4 + w;
    const float* xr = x + row * DM;
    float4 v0 = *(const float4*)&xr[lane * 4];
    float4 v1 = *(const float4*)&xr[256 + lane * 4];
    float sum = v0.x + v0.y + v0.z + v0.w + v1.x + v1.y + v1.z + v1.w;
#pragma unroll
    for (int off = 32; off > 0; off >>= 1) sum += __shfl_xor(sum, off, 64);
    float mu = sum * (1.0f / 512.0f);
    float d0[8] = {v0.x - mu, v0.y - mu, v0.z - mu, v0.w - mu,
                   v1.x - mu, v1.y - mu, v1.z - mu, v1.w - mu};
    float sq = 0.0f;
#pragma unroll
    for (int i = 0; i < 8; i++) sq = fmaf(d0[i], d0[i], sq);
#pragma unroll
    for (int off = 32; off > 0; off >>= 1) sq += __shfl_xor(sq, off, 64);
    float rs = rsqrtf(sq * (1.0f / 512.0f) + 1e-3f);
    float4 g0 = *(const float4*)&g[lane * 4];
    float4 g1 = *(const float4*)&g[256 + lane * 4];
    float4 b0 = *(const float4*)&bta[lane * 4];
    float4 b1 = *(const float4*)&bta[256 + lane * 4];
    ushort* orow = out + row * DM;
    ushort4 o0, o1;
    o0.x = f2bf(fmaf(d0[0] * rs, g0.x, b0.x));
    o0.y = f2bf(fmaf(d0[1] * rs, g0.y, b0.y));
    o0.z = f2bf(fmaf(d0[2] * rs, g0.z, b0.z));
    o0.w = f2bf(fmaf(d0[3] * rs, g0.w, b0.w));
    o1.x = f2bf(fmaf(d0[4] * rs, g1.x, b1.x));
    o1.y = f2bf(fmaf(d0[5] * rs, g1.y, b1.y));
    o1.z = f2bf(fmaf(d0[6] * rs, g1.z, b1.z));
    o1.w = f2bf(fmaf(d0[7] * rs, g1.w, b1.w));
    *(ushort4*)&orow[lane * 4] = o0;
    *(ushort4*)&orow[256 + lane * 4] = o1;
}

// ---------------------------------------------------------------------------
// bf16 MFMA GEMM (m97 recipe): A bf16 [M][K], Bt bf16 [N][K] (pre-transposed),
// 128x128 tile, BK=32, 256 thr = 4 waves, each wave a 64x64 quadrant (4x4
// 16x16x32 MFMA tiles). Staging via global_load_lds width=16.
// MODE: 0 = bf16 store; 1 = fp32 +=; 2 = bias+relu -> bf16; 3 = bias + fp32 +=
// ---------------------------------------------------------------------------
template <int MODE>
__global__ __launch_bounds__(256) void gemm_bf16(const ushort* __restrict__ A,
                                                 const ushort* __restrict__ Bt,
                                                 const float* __restrict__ bias,
                                                 void* __restrict__ Cv,
                                                 int M, int N, int K) {
    __shared__ __align__(16) ushort As[128 * 32];
    __shared__ __align__(16) ushort Bs[128 * 32];
    const int tid = threadIdx.x;
    const int lane = tid & 63;
    const int w = tid >> 6;
    const int m0 = blockIdx.y * 128, n0 = blockIdx.x * 128;
    const int wm = (w >> 1) * 64, wn = (w & 1) * 64;
    const int fm = lane & 15, fq = lane >> 4;

    f32x4 acc[4][4] = {};

    for (int kt = 0; kt < K; kt += 32) {
        __syncthreads();
#pragma unroll
        for (int u = 0; u < 2; u++) {
            int seg = w * 2 + u;
            int chunk = seg * 64 + lane;         // 16B chunk id, 0..511
            int row = chunk >> 2, c = chunk & 3;
            async16(&A[(size_t)(m0 + row) * K + kt + c * 8], (char*)As + chunk * 16);
            async16(&Bt[(size_t)(n0 + row) * K + kt + c * 8], (char*)Bs + chunk * 16);
        }
        __syncthreads();
        bf16x8 af[4], bfr[4];
#pragma unroll
        for (int i = 0; i < 4; i++)
            af[i] = *(const bf16x8*)&As[(wm + i * 16 + fm) * 32 + fq * 8];
#pragma unroll
        for (int j = 0; j < 4; j++)
            bfr[j] = *(const bf16x8*)&Bs[(wn + j * 16 + fm) * 32 + fq * 8];
#pragma unroll
        for (int i = 0; i < 4; i++)
#pragma unroll
            for (int j = 0; j < 4; j++)
                acc[i][j] = __builtin_amdgcn_mfma_f32_16x16x32_bf16(
                    af[i], bfr[j], acc[i][j], 0, 0, 0);
    }

#pragma unroll
    for (int i = 0; i < 4; i++) {
#pragma unroll
        for (int j = 0; j < 4; j++) {
            int col = n0 + wn + j * 16 + fm;
#pragma unroll
            for (int r = 0; r < 4; r++) {
                int row = m0 + wm + i * 16 + fq * 4 + r;
                float vv = acc[i][j][r];
                if constexpr (MODE == 0) {
                    ((ushort*)Cv)[(size_t)row * N + col] = f2bf(vv);
                } else if constexpr (MODE == 1) {
                    float* C = (float*)Cv;
                    C[(size_t)row * N + col] += vv;
                } else if constexpr (MODE == 2) {
                    vv += bias[col];
                    vv = fmaxf(vv, 0.0f);
                    ((ushort*)Cv)[(size_t)row * N + col] = f2bf(vv);
                } else {
                    float* C = (float*)Cv;
                    C[(size_t)row * N + col] += vv + bias[col];
                }
            }
        }
    }
}

// ---------------------------------------------------------------------------
// Flash attention, bf16 MFMA. Block = 256 thr = 4 waves, one (b,h), 64 q rows
// (16 per wave). Key tiles of 64. K LDS [key][dim], V LDS [dim][key] (from
// pre-transposed vT), both XOR-swizzled at 16B-chunk granularity.
// P round-trips through per-wave LDS (C-layout -> A-layout).
// ---------------------------------------------------------------------------
__global__ __launch_bounds__(256) void attn_mfma(const ushort* __restrict__ Q,
                                                 const ushort* __restrict__ Kg,
                                                 const ushort* __restrict__ Vt,
                                                 const int* __restrict__ mask,
                                                 ushort* __restrict__ O) {
    __shared__ __align__(16) ushort Kt[64 * 64];
    __shared__ __align__(16) ushort Vs[64 * 64];
    __shared__ __align__(16) ushort ps[4][16 * 64];
    __shared__ int msk[64];

    const int tid = threadIdx.x, lane = tid & 63, w = tid >> 6;
    const int h = blockIdx.y, b = blockIdx.z;
    const int q0 = blockIdx.x * 64 + w * 16;
    const int fm = lane & 15, fq = lane >> 4;
    ushort* pw = &ps[w][0];

    // Q A-frags (registers, reused across all key tiles)
    bf16x8 qf[2];
#pragma unroll
    for (int kk = 0; kk < 2; kk++)
        qf[kk] = *(const bf16x8*)&Q[(size_t)(b * SEQ + q0 + fm) * DM + h * HDIM +
                                    kk * 32 + fq * 8];

    f32x4 oacc[4] = {};
    float mrow[4], lrow[4];
#pragma unroll
    for (int r = 0; r < 4; r++) { mrow[r] = -INFINITY; lrow[r] = 0.0f; }

    for (int j0 = 0; j0 < SEQ; j0 += 64) {
        __syncthreads();
#pragma unroll
        for (int u = 0; u < 2; u++) {
            int ch = tid + u * 256;            // 0..511
            int rrow = ch >> 3, c = ch & 7;    // K: key row / dim chunk; V: dim row / key chunk
            const ushort* gk = &Kg[(size_t)(b * SEQ + j0 + rrow) * DM + h * HDIM + c * 8];
            *(uint4*)((char*)Kt + (rrow * 8 + (c ^ (rrow & 7))) * 16) = *(const uint4*)gk;
            const ushort* gv = &Vt[(size_t)((b * NH + h) * HDIM + rrow) * SEQ + j0 + c * 8];
            *(uint4*)((char*)Vs + (rrow * 8 + (c ^ (rrow & 7))) * 16) = *(const uint4*)gv;
        }
        if (tid < 64) msk[tid] = mask[b * SEQ + j0 + tid];
        __syncthreads();

        // ---- scores S = Q K^T ----
        f32x4 sc[4] = {};
#pragma unroll
        for (int nt = 0; nt < 4; nt++) {
            int key = nt * 16 + fm;
#pragma unroll
            for (int kk = 0; kk < 2; kk++) {
                bf16x8 kf = *(const bf16x8*)((char*)Kt +
                            (key * 8 + ((kk * 4 + fq) ^ (key & 7))) * 16);
                sc[nt] = __builtin_amdgcn_mfma_f32_16x16x32_bf16(qf[kk], kf, sc[nt], 0, 0, 0);
            }
        }

        // ---- mask + scale + online softmax ----
        float sv[4][4];
#pragma unroll
        for (int nt = 0; nt < 4; nt++) {
            int vm = msk[nt * 16 + fm];
#pragma unroll
            for (int r = 0; r < 4; r++)
                sv[nt][r] = vm ? sc[nt][r] * 0.125f : -1.0e9f;
        }
        float alpha[4];
#pragma unroll
        for (int r = 0; r < 4; r++) {
            float mx = fmaxf(fmaxf(sv[0][r], sv[1][r]), fmaxf(sv[2][r], sv[3][r]));
            mx = fmaxf(mx, __shfl_xor(mx, 1));
            mx = fmaxf(mx, __shfl_xor(mx, 2));
            mx = fmaxf(mx, __shfl_xor(mx, 4));
            mx = fmaxf(mx, __shfl_xor(mx, 8));
            float mn = fmaxf(mrow[r], mx);
            alpha[r] = __expf(mrow[r] - mn);
            mrow[r] = mn;
            float ls = 0.0f;
#pragma unroll
            for (int nt = 0; nt < 4; nt++) {
                float p = __expf(sv[nt][r] - mn);
                sv[nt][r] = p;
                ls += p;
            }
            ls += __shfl_xor(ls, 1);
            ls += __shfl_xor(ls, 2);
            ls += __shfl_xor(ls, 4);
            ls += __shfl_xor(ls, 8);
            lrow[r] = lrow[r] * alpha[r] + ls;
        }

        // ---- P to LDS (C-layout -> A-layout), swizzled ----
#pragma unroll
        for (int nt = 0; nt < 4; nt++) {
            int col = nt * 16 + fm;
#pragma unroll
            for (int r = 0; r < 4; r++) {
                int row = fq * 4 + r;
                pw[(row * 8 + ((col >> 3) ^ (row & 7))) * 8 + (col & 7)] = f2bf(sv[nt][r]);
            }
        }

        // rescale O accumulator
#pragma unroll
        for (int nt = 0; nt < 4; nt++)
#pragma unroll
            for (int r = 0; r < 4; r++) oacc[nt][r] *= alpha[r];

        // ---- O += P V ----
#pragma unroll
        for (int kk = 0; kk < 2; kk++) {
            bf16x8 pf = *(const bf16x8*)&pw[(fm * 8 + ((kk * 4 + fq) ^ (fm & 7))) * 8];
#pragma unroll
            for (int nt = 0; nt < 4; nt++) {
                int dim = nt * 16 + fm;
                bf16x8 vf = *(const bf16x8*)((char*)Vs +
                            (dim * 8 + ((kk * 4 + fq) ^ (dim & 7))) * 16);
                oacc[nt] = __builtin_amdgcn_mfma_f32_16x16x32_bf16(pf, vf, oacc[nt], 0, 0, 0);
            }
        }
    }

    float inv[4];
#pragma unroll
    for (int r = 0; r < 4; r++) inv[r] = 1.0f / lrow[r];
#pragma unroll
    for (int nt = 0; nt < 4; nt++)
#pragma unroll
        for (int r = 0; r < 4; r++)
            O[(size_t)(b * SEQ + q0 + fq * 4 + r) * DM + h * HDIM + nt * 16 + fm] =
                f2bf(oacc[nt][r] * inv[r]);
}

// ---------------------------------------------------------------------------
extern "C" void kernel_launch(void* const* d_in, const int* in_sizes, int n_in,
                              void* d_out, int out_size, void* d_ws, size_t ws_size,
                              hipStream_t stream) {
    const float* x_in = (const float*)d_in[0];
    const int* mask   = (const int*)d_in[1];
    const float* Wq   = (const float*)d_in[2];
    const float* Wk   = (const float*)d_in[3];
    const float* Wv   = (const float*)d_in[4];
    const float* Wo   = (const float*)d_in[5];
    const float* ln1g = (const float*)d_in[6];
    const float* ln1b = (const float*)d_in[7];
    const float* ln2g = (const float*)d_in[8];
    const float* ln2b = (const float*)d_in[9];
    const float* W1   = (const float*)d_in[10];
    const float* b1   = (const float*)d_in[11];
    const float* W2   = (const float*)d_in[12];
    const float* b2   = (const float*)d_in[13];

    float* x = (float*)d_out;  // fp32 residual stream
    ushort* wsb = (ushort*)d_ws;
    const size_t U = 1048576;
    ushort* WqT = wsb;            // [L][N=512][K=512]
    ushort* WkT = wsb + U;
    ushort* WvT = wsb + 2 * U;
    ushort* WoT = wsb + 3 * U;
    ushort* W1T = wsb + 4 * U;    // [L][2048][512]
    ushort* W2T = wsb + 8 * U;    // [L][512][2048]
    ushort* hb  = wsb + 12 * U;   // bf16 [8192][512]
    ushort* qb  = wsb + 16 * U;
    ushort* kbuf= wsb + 20 * U;
    ushort* vb  = wsb + 24 * U;
    ushort* ob  = wsb + 28 * U;
    ushort* vTb = wsb + 32 * U;   // bf16 [8][512][1024]
    ushort* f1b = qb;             // alias q..o (16M elems), dead during FFN

    // Weight convert+transpose (graph-safe: recomputed every launch)
    wtrans_kernel<<<dim3(16, 16, 4), 256, 0, stream>>>(Wq, WqT, 512, 512);
    wtrans_kernel<<<dim3(16, 16, 4), 256, 0, stream>>>(Wk, WkT, 512, 512);
    wtrans_kernel<<<dim3(16, 16, 4), 256, 0, stream>>>(Wv, WvT, 512, 512);
    wtrans_kernel<<<dim3(16, 16, 4), 256, 0, stream>>>(Wo, WoT, 512, 512);
    wtrans_kernel<<<dim3(64, 16, 4), 256, 0, stream>>>(W1, W1T, 512, 2048);
    wtrans_kernel<<<dim3(16, 64, 4), 256, 0, stream>>>(W2, W2T, 2048, 512);

    add_pos_kernel<<<(NTOK * DM / 4) / 256, 256, 0, stream>>>(x_in, x);

    dim3 gProj(4, 64);
    dim3 gFF1(16, 64);
    dim3 gAttn(16, NH, NB);
    dim3 gVtr(16, 32, 8);

    for (int l = 0; l < NLAYER; l++) {
        const size_t wOff  = (size_t)l * 262144;
        const size_t w1Off = (size_t)l * 1048576;

        ln_kernel<<<NTOK / 4, 256, 0, stream>>>(x, ln1g + l * DM, ln1b + l * DM, hb);
        gemm_bf16<0><<<gProj, 256, 0, stream>>>(hb, WqT + wOff, nullptr, qb, NTOK, DM, DM);
        gemm_bf16<0><<<gProj, 256, 0, stream>>>(hb, WkT + wOff, nullptr, kbuf, NTOK, DM, DM);
        gemm_bf16<0><<<gProj, 256, 0, stream>>>(hb, WvT + wOff, nullptr, vb, NTOK, DM, DM);
        vtrans_kernel<<<gVtr, 256, 0, stream>>>(vb, vTb);
        attn_mfma<<<gAttn, 256, 0, stream>>>(qb, kbuf, vTb, mask, ob);
        gemm_bf16<1><<<gProj, 256, 0, stream>>>(ob, WoT + wOff, nullptr, x, NTOK, DM, DM);
        ln_kernel<<<NTOK / 4, 256, 0, stream>>>(x, ln2g + l * DM, ln2b + l * DM, hb);
        gemm_bf16<2><<<gFF1, 256, 0, stream>>>(hb, W1T + w1Off, b1 + (size_t)l * DFF,
                                               f1b, NTOK, DFF, DM);
        gemm_bf16<3><<<gProj, 256, 0, stream>>>(f1b, W2T + w1Off, b2 + (size_t)l * DM,
                                                x, NTOK, DM, DFF);
    }
}

// Round 3
// 971.606 us; speedup vs baseline: 7.8319x; 1.1811x over previous
//
#include <hip/hip_runtime.h>
#include <math.h>

// Problem constants
#define NB 8
#define SEQ 1024
#define DM 512
#define NH 8
#define HDIM 64
#define DFF 2048
#define NLAYER 4
#define NTOK (NB * SEQ)   // 8192
#define QKVD 1536         // fused q|k|v row width

typedef __attribute__((ext_vector_type(8))) short bf16x8;
typedef __attribute__((ext_vector_type(4))) float f32x4;

__device__ __forceinline__ ushort f2bf(float f) {
    union { float f; unsigned u; } v; v.f = f;
    unsigned r = (v.u + 0x7FFF + ((v.u >> 16) & 1)) >> 16;  // RNE
    return (ushort)r;
}

// async global->LDS, 16B per lane
__device__ __forceinline__ void async16(const void* g, void* l) {
    __builtin_amdgcn_global_load_lds(
        (const __attribute__((address_space(1))) unsigned int*)g,
        (__attribute__((address_space(3))) unsigned int*)l, 16, 0, 0);
}

// ---------------------------------------------------------------------------
// Positional encoding add
// ---------------------------------------------------------------------------
__global__ __launch_bounds__(256) void add_pos_kernel(const float* __restrict__ x,
                                                      float* __restrict__ out) {
    int idx4 = blockIdx.x * blockDim.x + threadIdx.x;
    int base = idx4 * 4;
    int d = base & (DM - 1);
    int s = (base >> 9) & (SEQ - 1);
    float4 v = *(const float4*)&x[base];
    float r[4] = {v.x, v.y, v.z, v.w};
#pragma unroll
    for (int i = 0; i < 4; i++) {
        int dd = d + i;
        float pe;
        if (dd < 256) {
            float inv = powf(10000.0f, 2.0f * (float)dd / 512.0f);
            pe = sinf((float)s / inv);
        } else {
            float inv = powf(10000.0f, 2.0f * (float)(dd - 256) / 512.0f);
            pe = cosf((float)s / inv);
        }
        r[i] += pe;
    }
    *(float4*)&out[base] = make_float4(r[0], r[1], r[2], r[3]);
}

// ---------------------------------------------------------------------------
// Weight convert+transpose: src fp32 [L][K][N] -> dst bf16 rows at
// dst + l*layerStride + (rowOff + n)*K + k
// ---------------------------------------------------------------------------
__global__ __launch_bounds__(256) void wtrans_kernel(const float* __restrict__ src,
                                                     ushort* __restrict__ dst,
                                                     int K, int N, int rowOff,
                                                     int layerStride) {
    __shared__ float tile[32][36];
    int l = blockIdx.z;
    int kb = blockIdx.y * 32, nb = blockIdx.x * 32;
    const float* s = src + (size_t)l * K * N;
    ushort* d = dst + (size_t)l * layerStride;
    int r = threadIdx.x >> 3, c4 = (threadIdx.x & 7) * 4;
    float4 v = *(const float4*)&s[(size_t)(kb + r) * N + nb + c4];
    *(float4*)&tile[r][c4] = v;
    __syncthreads();
    ushort4 o;
    o.x = f2bf(tile[c4 + 0][r]);
    o.y = f2bf(tile[c4 + 1][r]);
    o.z = f2bf(tile[c4 + 2][r]);
    o.w = f2bf(tile[c4 + 3][r]);
    *(ushort4*)&d[(size_t)(rowOff + nb + r) * K + kb + c4] = o;
}

// ---------------------------------------------------------------------------
// bf16 transpose of V slice of qkv: qkv[b*SEQ+s][1024+c] -> vT[b][c][s]
// ---------------------------------------------------------------------------
__global__ __launch_bounds__(256) void vtrans_kernel(const ushort* __restrict__ qkv,
                                                     ushort* __restrict__ vT) {
    __shared__ ushort tile[32][36];
    int b = blockIdx.z;
    int s0 = blockIdx.y * 32, c0 = blockIdx.x * 32;
    int r = threadIdx.x >> 3, q4 = (threadIdx.x & 7) * 4;
    *(ushort4*)&tile[r][q4] =
        *(const ushort4*)&qkv[(size_t)(b * SEQ + s0 + r) * QKVD + 1024 + c0 + q4];
    __syncthreads();
    ushort4 o;
    o.x = tile[q4 + 0][r];
    o.y = tile[q4 + 1][r];
    o.z = tile[q4 + 2][r];
    o.w = tile[q4 + 3][r];
    *(ushort4*)&vT[(size_t)(b * DM + c0 + r) * SEQ + s0 + q4] = o;
}

// ---------------------------------------------------------------------------
// LayerNorm fp32 in -> bf16 out. One wave per row, 4 rows/block.
// ---------------------------------------------------------------------------
__global__ __launch_bounds__(256) void ln_kernel(const float* __restrict__ x,
                                                 const float* __restrict__ g,
                                                 const float* __restrict__ bta,
                                                 ushort* __restrict__ out) {
    int w = threadIdx.x >> 6;
    int lane = threadIdx.x & 63;
    size_t row = (size_t)blockIdx.x * 4 + w;
    const float* xr = x + row * DM;
    float4 v0 = *(const float4*)&xr[lane * 4];
    float4 v1 = *(const float4*)&xr[256 + lane * 4];
    float sum = v0.x + v0.y + v0.z + v0.w + v1.x + v1.y + v1.z + v1.w;
#pragma unroll
    for (int off = 32; off > 0; off >>= 1) sum += __shfl_xor(sum, off, 64);
    float mu = sum * (1.0f / 512.0f);
    float d0[8] = {v0.x - mu, v0.y - mu, v0.z - mu, v0.w - mu,
                   v1.x - mu, v1.y - mu, v1.z - mu, v1.w - mu};
    float sq = 0.0f;
#pragma unroll
    for (int i = 0; i < 8; i++) sq = fmaf(d0[i], d0[i], sq);
#pragma unroll
    for (int off = 32; off > 0; off >>= 1) sq += __shfl_xor(sq, off, 64);
    float rs = rsqrtf(sq * (1.0f / 512.0f) + 1e-3f);
    float4 g0 = *(const float4*)&g[lane * 4];
    float4 g1 = *(const float4*)&g[256 + lane * 4];
    float4 b0 = *(const float4*)&bta[lane * 4];
    float4 b1 = *(const float4*)&bta[256 + lane * 4];
    ushort* orow = out + row * DM;
    ushort4 o0, o1;
    o0.x = f2bf(fmaf(d0[0] * rs, g0.x, b0.x));
    o0.y = f2bf(fmaf(d0[1] * rs, g0.y, b0.y));
    o0.z = f2bf(fmaf(d0[2] * rs, g0.z, b0.z));
    o0.w = f2bf(fmaf(d0[3] * rs, g0.w, b0.w));
    o1.x = f2bf(fmaf(d0[4] * rs, g1.x, b1.x));
    o1.y = f2bf(fmaf(d0[5] * rs, g1.y, b1.y));
    o1.z = f2bf(fmaf(d0[6] * rs, g1.z, b1.z));
    o1.w = f2bf(fmaf(d0[7] * rs, g1.w, b1.w));
    *(ushort4*)&orow[lane * 4] = o0;
    *(ushort4*)&orow[256 + lane * 4] = o1;
}

// ---------------------------------------------------------------------------
// bf16 MFMA GEMM (m97 recipe), 128x128 tile, BK=32, 4 waves.
// MODE: 0 = bf16 store; 1 = fp32 +=; 2 = bias+relu -> bf16; 3 = bias + fp32 +=
// ---------------------------------------------------------------------------
template <int MODE>
__global__ __launch_bounds__(256) void gemm_bf16(const ushort* __restrict__ A,
                                                 const ushort* __restrict__ Bt,
                                                 const float* __restrict__ bias,
                                                 void* __restrict__ Cv,
                                                 int M, int N, int K) {
    __shared__ __align__(16) ushort As[128 * 32];
    __shared__ __align__(16) ushort Bs[128 * 32];
    const int tid = threadIdx.x;
    const int lane = tid & 63;
    const int w = tid >> 6;
    const int m0 = blockIdx.y * 128, n0 = blockIdx.x * 128;
    const int wm = (w >> 1) * 64, wn = (w & 1) * 64;
    const int fm = lane & 15, fq = lane >> 4;

    f32x4 acc[4][4] = {};

    for (int kt = 0; kt < K; kt += 32) {
        __syncthreads();
#pragma unroll
        for (int u = 0; u < 2; u++) {
            int seg = w * 2 + u;
            int chunk = seg * 64 + lane;         // 16B chunk id, 0..511
            int row = chunk >> 2, c = chunk & 3;
            async16(&A[(size_t)(m0 + row) * K + kt + c * 8], (char*)As + chunk * 16);
            async16(&Bt[(size_t)(n0 + row) * K + kt + c * 8], (char*)Bs + chunk * 16);
        }
        __syncthreads();
        bf16x8 af[4], bfr[4];
#pragma unroll
        for (int i = 0; i < 4; i++)
            af[i] = *(const bf16x8*)&As[(wm + i * 16 + fm) * 32 + fq * 8];
#pragma unroll
        for (int j = 0; j < 4; j++)
            bfr[j] = *(const bf16x8*)&Bs[(wn + j * 16 + fm) * 32 + fq * 8];
#pragma unroll
        for (int i = 0; i < 4; i++)
#pragma unroll
            for (int j = 0; j < 4; j++)
                acc[i][j] = __builtin_amdgcn_mfma_f32_16x16x32_bf16(
                    af[i], bfr[j], acc[i][j], 0, 0, 0);
    }

#pragma unroll
    for (int i = 0; i < 4; i++) {
#pragma unroll
        for (int j = 0; j < 4; j++) {
            int col = n0 + wn + j * 16 + fm;
#pragma unroll
            for (int r = 0; r < 4; r++) {
                int row = m0 + wm + i * 16 + fq * 4 + r;
                float vv = acc[i][j][r];
                if constexpr (MODE == 0) {
                    ((ushort*)Cv)[(size_t)row * N + col] = f2bf(vv);
                } else if constexpr (MODE == 1) {
                    float* C = (float*)Cv;
                    C[(size_t)row * N + col] += vv;
                } else if constexpr (MODE == 2) {
                    vv += bias[col];
                    vv = fmaxf(vv, 0.0f);
                    ((ushort*)Cv)[(size_t)row * N + col] = f2bf(vv);
                } else {
                    float* C = (float*)Cv;
                    C[(size_t)row * N + col] += vv + bias[col];
                }
            }
        }
    }
}

// ---------------------------------------------------------------------------
// Flash attention, S^T formulation. 256 thr = 4 waves, one (b,h), 64 q rows
// (16/wave, q = lane&15). S^T = K·Q^T puts a whole q-column in each lane:
// softmax reductions are 15 VALU ops + 2 shuffles; P^T is key-contiguous per
// lane -> 4 ds_write_b64 + 2 ds_read_b128. O^T = V^T·P^T.
// ---------------------------------------------------------------------------
__global__ __launch_bounds__(256) void attn_mfma(const ushort* __restrict__ QKV,
                                                 const ushort* __restrict__ Vt,
                                                 const int* __restrict__ mask,
                                                 ushort* __restrict__ O) {
    __shared__ __align__(16) ushort Kt[64 * 64];
    __shared__ __align__(16) ushort Vs[64 * 64];
    __shared__ __align__(16) ushort ps[4][16 * 72];  // per-wave P^T [q][key], stride 72
    __shared__ float mskf[64];

    const int tid = threadIdx.x, lane = tid & 63, w = tid >> 6;
    const int h = blockIdx.y, b = blockIdx.z;
    const int q0 = blockIdx.x * 64 + w * 16;
    const int fm = lane & 15, fq = lane >> 4;
    ushort* pw = &ps[w][0];

    // Q as B-fragment: lane: n = q0+fm, k = kk*32 + fq*8 + j
    bf16x8 qf[2];
#pragma unroll
    for (int kk = 0; kk < 2; kk++)
        qf[kk] = *(const bf16x8*)&QKV[(size_t)(b * SEQ + q0 + fm) * QKVD + h * HDIM +
                                      kk * 32 + fq * 8];

    f32x4 oacc[4] = {};   // O^T: col = q (fm), rows dim = nt*16 + fq*4 + r
    float mrow = -INFINITY, lrow = 0.0f;

    for (int j0 = 0; j0 < SEQ; j0 += 64) {
        __syncthreads();
#pragma unroll
        for (int u = 0; u < 2; u++) {
            int ch = tid + u * 256;            // 0..511
            int rrow = ch >> 3, c = ch & 7;
            const ushort* gk = &QKV[(size_t)(b * SEQ + j0 + rrow) * QKVD + 512 +
                                    h * HDIM + c * 8];
            *(uint4*)((char*)Kt + (rrow * 8 + (c ^ (rrow & 7))) * 16) = *(const uint4*)gk;
            const ushort* gv = &Vt[(size_t)((b * NH + h) * HDIM + rrow) * SEQ + j0 + c * 8];
            *(uint4*)((char*)Vs + (rrow * 8 + (c ^ (rrow & 7))) * 16) = *(const uint4*)gv;
        }
        if (tid < 64) mskf[tid] = mask[b * SEQ + j0 + tid] ? 1.0f : 0.0f;
        __syncthreads();

        // ---- S^T = K Q^T : lane holds q-col fm, keys nt*16 + fq*4 + r ----
        f32x4 sc[4] = {};
#pragma unroll
        for (int nt = 0; nt < 4; nt++) {
            int key = nt * 16 + fm;
#pragma unroll
            for (int kk = 0; kk < 2; kk++) {
                bf16x8 kf = *(const bf16x8*)((char*)Kt +
                            (key * 8 + ((kk * 4 + fq) ^ (key & 7))) * 16);
                sc[nt] = __builtin_amdgcn_mfma_f32_16x16x32_bf16(kf, qf[kk], sc[nt], 0, 0, 0);
            }
        }

        // ---- online softmax over the lane's 16 keys ----
        float sv[4][4];
        float mx = -INFINITY;
#pragma unroll
        for (int nt = 0; nt < 4; nt++)
#pragma unroll
            for (int r = 0; r < 4; r++) {
                sv[nt][r] = sc[nt][r] * 0.125f;
                mx = fmaxf(mx, sv[nt][r]);
            }
        mx = fmaxf(mx, __shfl_xor(mx, 16));
        mx = fmaxf(mx, __shfl_xor(mx, 32));
        float mn = fmaxf(mrow, mx);
        float alpha = __expf(mrow - mn);
        mrow = mn;

        float ls = 0.0f;
#pragma unroll
        for (int nt = 0; nt < 4; nt++) {
            f32x4 mv = *(const f32x4*)&mskf[nt * 16 + fq * 4];
#pragma unroll
            for (int r = 0; r < 4; r++) {
                float p = __expf(sv[nt][r] - mn) * mv[r];
                sv[nt][r] = p;
                ls += p;
            }
        }
        ls += __shfl_xor(ls, 16);
        ls += __shfl_xor(ls, 32);
        lrow = lrow * alpha + ls;

        // ---- P^T to per-wave LDS: pw[q=fm][key], trunc-to-bf16 packed ----
#pragma unroll
        for (int nt = 0; nt < 4; nt++) {
            union { float f; unsigned u; } a0, a1, a2, a3;
            a0.f = sv[nt][0]; a1.f = sv[nt][1]; a2.f = sv[nt][2]; a3.f = sv[nt][3];
            unsigned d0 = (a0.u >> 16) | (a1.u & 0xFFFF0000u);
            unsigned d1 = (a2.u >> 16) | (a3.u & 0xFFFF0000u);
            *(uint2*)&pw[fm * 72 + nt * 16 + fq * 4] = make_uint2(d0, d1);
        }

        // rescale O accumulator (alpha is per-lane scalar)
#pragma unroll
        for (int nt = 0; nt < 4; nt++)
#pragma unroll
            for (int r = 0; r < 4; r++) oacc[nt][r] *= alpha;

        // ---- O^T += V^T P^T ----
#pragma unroll
        for (int kk = 0; kk < 2; kk++) {
            bf16x8 pf = *(const bf16x8*)&pw[fm * 72 + kk * 32 + fq * 8];
#pragma unroll
            for (int nt = 0; nt < 4; nt++) {
                int dim = nt * 16 + fm;
                bf16x8 vf = *(const bf16x8*)((char*)Vs +
                            (dim * 8 + ((kk * 4 + fq) ^ (dim & 7))) * 16);
                oacc[nt] = __builtin_amdgcn_mfma_f32_16x16x32_bf16(vf, pf, oacc[nt], 0, 0, 0);
            }
        }
    }

    float inv = 1.0f / lrow;
#pragma unroll
    for (int nt = 0; nt < 4; nt++) {
        ushort4 o;
        o.x = f2bf(oacc[nt][0] * inv);
        o.y = f2bf(oacc[nt][1] * inv);
        o.z = f2bf(oacc[nt][2] * inv);
        o.w = f2bf(oacc[nt][3] * inv);
        *(ushort4*)&O[(size_t)(b * SEQ + q0 + fm) * DM + h * HDIM + nt * 16 + fq * 4] = o;
    }
}

// ---------------------------------------------------------------------------
extern "C" void kernel_launch(void* const* d_in, const int* in_sizes, int n_in,
                              void* d_out, int out_size, void* d_ws, size_t ws_size,
                              hipStream_t stream) {
    const float* x_in = (const float*)d_in[0];
    const int* mask   = (const int*)d_in[1];
    const float* Wq   = (const float*)d_in[2];
    const float* Wk   = (const float*)d_in[3];
    const float* Wv   = (const float*)d_in[4];
    const float* Wo   = (const float*)d_in[5];
    const float* ln1g = (const float*)d_in[6];
    const float* ln1b = (const float*)d_in[7];
    const float* ln2g = (const float*)d_in[8];
    const float* ln2b = (const float*)d_in[9];
    const float* W1   = (const float*)d_in[10];
    const float* b1   = (const float*)d_in[11];
    const float* W2   = (const float*)d_in[12];
    const float* b2   = (const float*)d_in[13];

    float* x = (float*)d_out;  // fp32 residual stream
    ushort* wsb = (ushort*)d_ws;
    const size_t U = 1048576;
    ushort* WqkvT = wsb;            // [L][1536][512]  (3U)
    ushort* WoT   = wsb + 3 * U;    // [L][512][512]   (1U)
    ushort* W1T   = wsb + 4 * U;    // [L][2048][512]  (4U)
    ushort* W2T   = wsb + 8 * U;    // [L][512][2048]  (4U)
    ushort* hb    = wsb + 12 * U;   // bf16 [8192][512]
    ushort* qkv   = wsb + 16 * U;   // bf16 [8192][1536] (12U)
    ushort* ob    = wsb + 28 * U;   // bf16 [8192][512]
    ushort* vTb   = wsb + 32 * U;   // bf16 [8][512][1024]
    ushort* f1b   = qkv;            // 16U alias (qkv+ob), dead during FFN

    // Weight convert+transpose (graph-safe: every launch)
    wtrans_kernel<<<dim3(16, 16, 4), 256, 0, stream>>>(Wq, WqkvT, 512, 512, 0, 786432);
    wtrans_kernel<<<dim3(16, 16, 4), 256, 0, stream>>>(Wk, WqkvT, 512, 512, 512, 786432);
    wtrans_kernel<<<dim3(16, 16, 4), 256, 0, stream>>>(Wv, WqkvT, 512, 512, 1024, 786432);
    wtrans_kernel<<<dim3(16, 16, 4), 256, 0, stream>>>(Wo, WoT, 512, 512, 0, 262144);
    wtrans_kernel<<<dim3(64, 16, 4), 256, 0, stream>>>(W1, W1T, 512, 2048, 0, 1048576);
    wtrans_kernel<<<dim3(16, 64, 4), 256, 0, stream>>>(W2, W2T, 2048, 512, 0, 1048576);

    add_pos_kernel<<<(NTOK * DM / 4) / 256, 256, 0, stream>>>(x_in, x);

    dim3 gQKV(QKVD / 128, NTOK / 128);   // (12, 64)
    dim3 gProj(DM / 128, NTOK / 128);    // (4, 64)
    dim3 gFF1(DFF / 128, NTOK / 128);    // (16, 64)
    dim3 gAttn(SEQ / 64, NH, NB);        // (16, 8, 8)
    dim3 gVtr(16, 32, 8);

    for (int l = 0; l < NLAYER; l++) {
        const size_t wOff   = (size_t)l * 262144;
        const size_t wqkvOff= (size_t)l * 786432;
        const size_t w1Off  = (size_t)l * 1048576;

        ln_kernel<<<NTOK / 4, 256, 0, stream>>>(x, ln1g + l * DM, ln1b + l * DM, hb);
        gemm_bf16<0><<<gQKV, 256, 0, stream>>>(hb, WqkvT + wqkvOff, nullptr, qkv,
                                               NTOK, QKVD, DM);
        vtrans_kernel<<<gVtr, 256, 0, stream>>>(qkv, vTb);
        attn_mfma<<<gAttn, 256, 0, stream>>>(qkv, vTb, mask, ob);
        gemm_bf16<1><<<gProj, 256, 0, stream>>>(ob, WoT + wOff, nullptr, x, NTOK, DM, DM);
        ln_kernel<<<NTOK / 4, 256, 0, stream>>>(x, ln2g + l * DM, ln2b + l * DM, hb);
        gemm_bf16<2><<<gFF1, 256, 0, stream>>>(hb, W1T + w1Off, b1 + (size_t)l * DFF,
                                               f1b, NTOK, DFF, DM);
        gemm_bf16<3><<<gProj, 256, 0, stream>>>(f1b, W2T + w1Off, b2 + (size_t)l * DM,
                                                x, NTOK, DM, DFF);
    }
}